// Round 3
// baseline (640.936 us; speedup 1.0000x reference)
//
#include <hip/hip_runtime.h>
#include <stdint.h>

typedef float vfloat4 __attribute__((ext_vector_type(4)));

// B=1024, N=8192, D=128
// out layout (floats): quantized[1024][1024][128] | ind[1024] | loss[1]
static const long long QN       = 134217728LL;
static const long long IND_OFF  = QN;
static const long long LOSS_OFF = QN + 1024;
// Scratch carved out of the quantized region (overwritten by k_bcast later).
// Avoids q rows at i*131072+[0,128).
static const long long PVAL_OFF = 1022LL * 131072 + 128; // 65536 floats (1024x64)
static const long long PIDX_OFF = 1023LL * 131072 + 128; // 65536 ints

// ws layout (floats): w2[8192] | x2[1024] | sx[128] | sq[128] | Sx2 | Sq2
#define WS_W2  0
#define WS_X2  8192
#define WS_SX  9216
#define WS_SQ  9344
#define WS_SX2 9472
#define WS_SQ2 9473

__global__ void k_zero(float* __restrict__ ws) {
    int i = blockIdx.x * 256 + threadIdx.x;
    if (i < 258) ws[WS_SX + i] = 0.0f;
}

// sq[n] = ||row_n||^2 (used for both W [grid 32] and x [grid 4])
__global__ void k_rowsq(const float* __restrict__ P, float* __restrict__ o) {
    int n = blockIdx.x * 256 + threadIdx.x;
    const float4* pr = (const float4*)P + (size_t)n * 32;
    float s = 0.0f;
#pragma unroll 8
    for (int t = 0; t < 32; ++t) {
        float4 v = pr[t];
        s += v.x * v.x + v.y * v.y + v.z * v.z + v.w * v.w;
    }
    o[n] = s;
}

// Column sums + total sum-of-squares over a 1024 x 128 matrix with row stride.
__global__ void k_colsums(const float* __restrict__ p, long long rowStride,
                          float* __restrict__ scol, float* __restrict__ s2out) {
    __shared__ float sh[256];
    const int tid = threadIdx.x;
    const int d = tid & 127, g = tid >> 7;
    const int r0 = blockIdx.x * 128;
    float sum = 0.0f, s2 = 0.0f;
    for (int r = r0 + g; r < r0 + 128; r += 2) {
        float v = p[(size_t)r * rowStride + d];
        sum += v;
        s2 += v * v;
    }
    sh[tid] = sum;
    __syncthreads();
    if (tid < 128) atomicAdd(&scol[d], sh[tid] + sh[tid + 128]);
    __syncthreads();
    sh[tid] = s2;
    __syncthreads();
    for (int s = 128; s > 0; s >>= 1) {
        if (tid < s) sh[tid] += sh[tid + s];
        __syncthreads();
    }
    if (tid == 0) atomicAdd(s2out, sh[0]);
}

// dist[m][n] replicated with the reference's fp32 rounding:
//   t = x2[m] - 2*dot(x_m,W_n)  (fp32; product exact so FMA == mul+sub)
//   s = t + w2[n]               (fp32)
// Per-block partial argmin (first-occurrence tie-break) over a 128-col chunk.
__global__ __launch_bounds__(256) void k_score(
    const float* __restrict__ x, const float* __restrict__ W,
    const float* __restrict__ w2, const float* __restrict__ x2,
    float* __restrict__ pval, int* __restrict__ pidx) {
    __shared__ float Xs[32][132];  // [k][m], +4 pad
    __shared__ float Wst[32][132]; // [k][n]
    const int tid = threadIdx.x;
    const int tx = tid & 15, ty = tid >> 4;
    const int n0 = blockIdx.x * 128, m0 = blockIdx.y * 128;
    const float4* xv = (const float4*)x;
    const float4* wv = (const float4*)W;

    float acc[8][8];
#pragma unroll
    for (int i = 0; i < 8; ++i)
#pragma unroll
        for (int j = 0; j < 8; ++j) acc[i][j] = 0.0f;

    for (int kc = 0; kc < 4; ++kc) {
#pragma unroll
        for (int it = 0; it < 4; ++it) {
            int f = it * 256 + tid;
            int m = f >> 3, kq = f & 7;
            float4 a = xv[(size_t)(m0 + m) * 32 + kc * 8 + kq];
            float4 b = wv[(size_t)(n0 + m) * 32 + kc * 8 + kq];
            Xs[kq * 4 + 0][m] = a.x;
            Xs[kq * 4 + 1][m] = a.y;
            Xs[kq * 4 + 2][m] = a.z;
            Xs[kq * 4 + 3][m] = a.w;
            Wst[kq * 4 + 0][m] = b.x;
            Wst[kq * 4 + 1][m] = b.y;
            Wst[kq * 4 + 2][m] = b.z;
            Wst[kq * 4 + 3][m] = b.w;
        }
        __syncthreads();
#pragma unroll 8
        for (int k = 0; k < 32; ++k) {
            float4 a0 = *(const float4*)&Xs[k][ty * 8];
            float4 a1 = *(const float4*)&Xs[k][ty * 8 + 4];
            float4 b0 = *(const float4*)&Wst[k][tx * 8];
            float4 b1 = *(const float4*)&Wst[k][tx * 8 + 4];
            float af[8] = {a0.x, a0.y, a0.z, a0.w, a1.x, a1.y, a1.z, a1.w};
            float bf[8] = {b0.x, b0.y, b0.z, b0.w, b1.x, b1.y, b1.z, b1.w};
#pragma unroll
            for (int i = 0; i < 8; ++i)
#pragma unroll
                for (int j = 0; j < 8; ++j) acc[i][j] += af[i] * bf[j];
        }
        __syncthreads();
    }

    float w2v[8];
#pragma unroll
    for (int j = 0; j < 8; ++j) w2v[j] = w2[n0 + tx * 8 + j];

#pragma unroll
    for (int i = 0; i < 8; ++i) {
        const int row = m0 + ty * 8 + i;
        const float xxv = x2[row];
        float bestv;
        int besti = n0 + tx * 8;
        {
            float t = xxv - 2.0f * acc[i][0];
            bestv = t + w2v[0];
        }
#pragma unroll
        for (int j = 1; j < 8; ++j) {
            float t = xxv - 2.0f * acc[i][j];
            float s = t + w2v[j];
            if (s < bestv) { bestv = s; besti = n0 + tx * 8 + j; }
        }
        // reduce over tx (lane bits 0..3), tie-break lowest index
        for (int off = 1; off < 16; off <<= 1) {
            float ov = __shfl_xor(bestv, off, 64);
            int oi = __shfl_xor(besti, off, 64);
            if (ov < bestv || (ov == bestv && oi < besti)) { bestv = ov; besti = oi; }
        }
        if (tx == 0) {
            pval[row * 64 + blockIdx.x] = bestv;
            pidx[row * 64 + blockIdx.x] = besti;
        }
    }
}

// Final argmin per row (first-occurrence), write ind (as float), gather q into quantized[i][0][:]
__global__ void k_argmin(const float* __restrict__ W, const float* __restrict__ pval,
                         const int* __restrict__ pidx, float* __restrict__ out) {
    int r = blockIdx.x * 256 + threadIdx.x; // 0..1023
    float bestv = pval[r * 64];
    int besti = pidx[r * 64];
    for (int c = 1; c < 64; ++c) {
        float v = pval[r * 64 + c];
        if (v < bestv) { bestv = v; besti = pidx[r * 64 + c]; }
    }
    out[IND_OFF + r] = (float)besti;
    float4* q = (float4*)out + (size_t)r * 32768;
    const float4* wr = (const float4*)W + (size_t)besti * 32;
#pragma unroll 8
    for (int t = 0; t < 32; ++t) q[t] = wr[t];
}

__global__ void k_loss(const float* __restrict__ ws, float* __restrict__ out) {
    __shared__ float sh[128];
    int tid = threadIdx.x; // 128 threads
    sh[tid] = ws[WS_SX + tid] * ws[WS_SQ + tid];
    __syncthreads();
    for (int s = 64; s > 0; s >>= 1) {
        if (tid < s) sh[tid] += sh[tid + s];
        __syncthreads();
    }
    if (tid == 0) {
        double dot = (double)sh[0];
        double Sx2 = (double)ws[WS_SX2], Sq2 = (double)ws[WS_SQ2];
        double loss = 1.25 * (1024.0 * Sx2 + 1024.0 * Sq2 - 2.0 * dot) / 134217728.0;
        out[LOSS_OFF] = (float)loss;
    }
}

// quantized[i][j][:] = q[i] for all j. 537 MB stream write.
__global__ __launch_bounds__(256) void k_bcast(float* __restrict__ out) {
    const int i = blockIdx.x;
    const int t = threadIdx.x & 31;
    const int j0 = threadIdx.x >> 5;
    const vfloat4* src = (const vfloat4*)out + (size_t)i * 32768;
    vfloat4 q = src[t];
    vfloat4* dst = (vfloat4*)out + (size_t)i * 32768 + t;
    for (int j = j0; j < 1024; j += 8) {
        __builtin_nontemporal_store(q, dst + (size_t)j * 32);
    }
}

extern "C" void kernel_launch(void* const* d_in, const int* in_sizes, int n_in,
                              void* d_out, int out_size, void* d_ws, size_t ws_size,
                              hipStream_t stream) {
    const float* x = (const float*)d_in[0]; // 1024 x 128
    const float* W = (const float*)d_in[1]; // 8192 x 128
    float* out = (float*)d_out;
    float* ws = (float*)d_ws;

    hipLaunchKernelGGL(k_zero, dim3(2), dim3(256), 0, stream, ws);
    hipLaunchKernelGGL(k_rowsq, dim3(32), dim3(256), 0, stream, W, ws + WS_W2);
    hipLaunchKernelGGL(k_rowsq, dim3(4), dim3(256), 0, stream, x, ws + WS_X2);
    hipLaunchKernelGGL(k_colsums, dim3(8), dim3(256), 0, stream, x, (long long)128,
                       ws + WS_SX, ws + WS_SX2);
    hipLaunchKernelGGL(k_score, dim3(64, 8), dim3(256), 0, stream, x, W,
                       ws + WS_W2, ws + WS_X2, out + PVAL_OFF, (int*)(out + PIDX_OFF));
    hipLaunchKernelGGL(k_argmin, dim3(4), dim3(256), 0, stream, W, out + PVAL_OFF,
                       (const int*)(out + PIDX_OFF), out);
    hipLaunchKernelGGL(k_colsums, dim3(8), dim3(256), 0, stream, out, (long long)131072,
                       ws + WS_SQ, ws + WS_SQ2);
    hipLaunchKernelGGL(k_loss, dim3(1), dim3(128), 0, stream, ws, out);
    hipLaunchKernelGGL(k_bcast, dim3(1024), dim3(256), 0, stream, out);
}

// Round 4
// 635.879 us; speedup vs baseline: 1.0080x; 1.0080x over previous
//
#include <hip/hip_runtime.h>
#include <stdint.h>

typedef float vfloat4 __attribute__((ext_vector_type(4)));

// B=1024, N=8192, D=128
// out layout (floats): quantized[1024][1024][128] | ind[1024] | loss[1]
static const long long QN       = 134217728LL;
static const long long IND_OFF  = QN;
static const long long LOSS_OFF = QN + 1024;
// Scratch carved out of the quantized region (consumed by k_argmin, then
// overwritten by k_bcast). Avoids q rows at i*131072+[0,128).
static const long long PVAL_OFF = 1022LL * 131072 + 128; // 65536 floats (1024x64)
static const long long PIDX_OFF = 1023LL * 131072 + 128; // 65536 ints

// ws layout (floats): w2[8192] | x2[1024] | sx[128] | sq[128] | Sq2
#define WS_W2  0
#define WS_X2  8192
#define WS_SX  9216
#define WS_SQ  9344
#define WS_SQ2 9472

// Fused prep: blocks 0-31 w2 rows; 32-35 x2 rows; 36-39 x column-sums
// (each block owns 32 columns — no atomics) + block 36 zeros sq/Sq2.
__global__ __launch_bounds__(256) void k_prep(const float* __restrict__ x,
                                              const float* __restrict__ W,
                                              float* __restrict__ ws) {
    const int b = blockIdx.x, tid = threadIdx.x;
    if (b < 36) {
        const float4* pr = (b < 32) ? ((const float4*)W + (size_t)(b * 256 + tid) * 32)
                                    : ((const float4*)x + (size_t)((b - 32) * 256 + tid) * 32);
        float s = 0.0f;
#pragma unroll 8
        for (int t = 0; t < 32; ++t) {
            float4 v = pr[t];
            s += v.x * v.x + v.y * v.y + v.z * v.z + v.w * v.w;
        }
        if (b < 32) ws[WS_W2 + b * 256 + tid] = s;
        else        ws[WS_X2 + (b - 32) * 256 + tid] = s;
    } else {
        __shared__ float sh[8][32];
        const int c = tid & 31, g = tid >> 5;
        const int col = (b - 36) * 32 + c;
        float sum = 0.0f;
        for (int r = g; r < 1024; r += 8) sum += x[(size_t)r * 128 + col];
        sh[g][c] = sum;
        __syncthreads();
        if (g == 0) {
            float t = 0.0f;
#pragma unroll
            for (int gg = 0; gg < 8; ++gg) t += sh[gg][c];
            ws[WS_SX + col] = t;
        }
        if (b == 36 && tid < 129) ws[WS_SQ + tid] = 0.0f; // sq[128] + Sq2
    }
}

// dist[m][n] with the reference's fp32 rounding:
//   t = x2[m] - 2*dot(x_m,W_n); s = t + w2[n]
// Per-block partial argmin (first-occurrence tie-break) over a 128-col chunk.
// VERIFIED CORRECT in round 3 — do not perturb the numerics path.
__global__ __launch_bounds__(256) void k_score(
    const float* __restrict__ x, const float* __restrict__ W,
    const float* __restrict__ w2, const float* __restrict__ x2,
    float* __restrict__ pval, int* __restrict__ pidx) {
    __shared__ float Xs[32][132];  // [k][m], +4 pad
    __shared__ float Wst[32][132]; // [k][n]
    const int tid = threadIdx.x;
    const int tx = tid & 15, ty = tid >> 4;
    const int n0 = blockIdx.x * 128, m0 = blockIdx.y * 128;
    const float4* xv = (const float4*)x;
    const float4* wv = (const float4*)W;

    float acc[8][8];
#pragma unroll
    for (int i = 0; i < 8; ++i)
#pragma unroll
        for (int j = 0; j < 8; ++j) acc[i][j] = 0.0f;

    for (int kc = 0; kc < 4; ++kc) {
#pragma unroll
        for (int it = 0; it < 4; ++it) {
            int f = it * 256 + tid;
            int m = f >> 3, kq = f & 7;
            float4 a = xv[(size_t)(m0 + m) * 32 + kc * 8 + kq];
            float4 b = wv[(size_t)(n0 + m) * 32 + kc * 8 + kq];
            Xs[kq * 4 + 0][m] = a.x;
            Xs[kq * 4 + 1][m] = a.y;
            Xs[kq * 4 + 2][m] = a.z;
            Xs[kq * 4 + 3][m] = a.w;
            Wst[kq * 4 + 0][m] = b.x;
            Wst[kq * 4 + 1][m] = b.y;
            Wst[kq * 4 + 2][m] = b.z;
            Wst[kq * 4 + 3][m] = b.w;
        }
        __syncthreads();
#pragma unroll 8
        for (int k = 0; k < 32; ++k) {
            float4 a0 = *(const float4*)&Xs[k][ty * 8];
            float4 a1 = *(const float4*)&Xs[k][ty * 8 + 4];
            float4 b0 = *(const float4*)&Wst[k][tx * 8];
            float4 b1 = *(const float4*)&Wst[k][tx * 8 + 4];
            float af[8] = {a0.x, a0.y, a0.z, a0.w, a1.x, a1.y, a1.z, a1.w};
            float bf[8] = {b0.x, b0.y, b0.z, b0.w, b1.x, b1.y, b1.z, b1.w};
#pragma unroll
            for (int i = 0; i < 8; ++i)
#pragma unroll
                for (int j = 0; j < 8; ++j) acc[i][j] += af[i] * bf[j];
        }
        __syncthreads();
    }

    float w2v[8];
#pragma unroll
    for (int j = 0; j < 8; ++j) w2v[j] = w2[n0 + tx * 8 + j];

#pragma unroll
    for (int i = 0; i < 8; ++i) {
        const int row = m0 + ty * 8 + i;
        const float xxv = x2[row];
        float bestv;
        int besti = n0 + tx * 8;
        {
            float t = xxv - 2.0f * acc[i][0];
            bestv = t + w2v[0];
        }
#pragma unroll
        for (int j = 1; j < 8; ++j) {
            float t = xxv - 2.0f * acc[i][j];
            float s = t + w2v[j];
            if (s < bestv) { bestv = s; besti = n0 + tx * 8 + j; }
        }
        for (int off = 1; off < 16; off <<= 1) {
            float ov = __shfl_xor(bestv, off, 64);
            int oi = __shfl_xor(besti, off, 64);
            if (ov < bestv || (ov == bestv && oi < besti)) { bestv = ov; besti = oi; }
        }
        if (tx == 0) {
            pval[row * 64 + blockIdx.x] = bestv;
            pidx[row * 64 + blockIdx.x] = besti;
        }
    }
}

// Final argmin per row (first-occurrence), write ind, gather q into
// quantized[i][0][:], and fold in: Sq2 += w2[ind] (exact identity),
// sq[d] += q[r][d] via in-register butterfly + one atomic per wave.
__global__ __launch_bounds__(256) void k_argmin(
    const float* __restrict__ W, const float* __restrict__ w2,
    const float* __restrict__ pval, const int* __restrict__ pidx,
    float* __restrict__ out, float* __restrict__ ws) {
    const int r = blockIdx.x * 256 + threadIdx.x; // 0..1023
    float bestv = pval[r * 64];
    int besti = pidx[r * 64];
    for (int c = 1; c < 64; ++c) {
        float v = pval[r * 64 + c];
        if (v < bestv) { bestv = v; besti = pidx[r * 64 + c]; }
    }
    out[IND_OFF + r] = (float)besti;

    // Sq2 contribution: ||q_r||^2 == w2[ind_r]
    float q2 = w2[besti];
    for (int off = 1; off < 64; off <<= 1) q2 += __shfl_xor(q2, off, 64);
    if ((threadIdx.x & 63) == 0) atomicAdd(ws + WS_SQ2, q2);

    float4* q = (float4*)out + (size_t)r * 32768;
    const float4* wr = (const float4*)W + (size_t)besti * 32;
    for (int t = 0; t < 32; ++t) {
        float4 v = wr[t];
        q[t] = v;
        float4 s = v;
        for (int off = 1; off < 64; off <<= 1) {
            s.x += __shfl_xor(s.x, off, 64);
            s.y += __shfl_xor(s.y, off, 64);
            s.z += __shfl_xor(s.z, off, 64);
            s.w += __shfl_xor(s.w, off, 64);
        }
        if ((threadIdx.x & 63) == 0) {
            atomicAdd(ws + WS_SQ + t * 4 + 0, s.x);
            atomicAdd(ws + WS_SQ + t * 4 + 1, s.y);
            atomicAdd(ws + WS_SQ + t * 4 + 2, s.z);
            atomicAdd(ws + WS_SQ + t * 4 + 3, s.w);
        }
    }
}

// quantized[i][j][:] = q[i]. 537 MB stream write, plain stores (fill kernel
// proves plain stores sustain ~6.3 TB/s). Block = one (i, j-quarter) slice.
// Block 0 additionally computes the loss scalar first.
__global__ __launch_bounds__(256) void k_bcast(float* __restrict__ out,
                                               const float* __restrict__ ws) {
    const int bid = blockIdx.x, tid = threadIdx.x;
    if (bid == 0) {
        __shared__ float sh[256];
        float dotv = (tid < 128) ? ws[WS_SX + tid] * ws[WS_SQ + tid] : 0.0f;
        float sx2 = 0.0f;
        for (int r = tid; r < 1024; r += 256) sx2 += ws[WS_X2 + r];
        sh[tid] = dotv;
        __syncthreads();
        for (int s = 128; s > 0; s >>= 1) {
            if (tid < s) sh[tid] += sh[tid + s];
            __syncthreads();
        }
        const float dot = sh[0];
        __syncthreads();
        sh[tid] = sx2;
        __syncthreads();
        for (int s = 128; s > 0; s >>= 1) {
            if (tid < s) sh[tid] += sh[tid + s];
            __syncthreads();
        }
        if (tid == 0) {
            double Sx2 = (double)sh[0], Sq2 = (double)ws[WS_SQ2];
            double loss = 1.25 * (1024.0 * Sx2 + 1024.0 * Sq2 - 2.0 * (double)dot) / 134217728.0;
            out[LOSS_OFF] = (float)loss;
        }
        __syncthreads();
    }
    const int i = bid >> 2;
    const int quarter = bid & 3;
    const int t = tid & 31;
    const int jend = quarter * 256 + 256;
    const vfloat4* src = (const vfloat4*)out + (size_t)i * 32768;
    vfloat4 qv = src[t];
    vfloat4* dst = (vfloat4*)out + (size_t)i * 32768 + t;
    for (int j = quarter * 256 + (tid >> 5); j < jend; j += 8) {
        dst[(size_t)j * 32] = qv;
    }
}

extern "C" void kernel_launch(void* const* d_in, const int* in_sizes, int n_in,
                              void* d_out, int out_size, void* d_ws, size_t ws_size,
                              hipStream_t stream) {
    const float* x = (const float*)d_in[0]; // 1024 x 128
    const float* W = (const float*)d_in[1]; // 8192 x 128
    float* out = (float*)d_out;
    float* ws = (float*)d_ws;

    hipLaunchKernelGGL(k_prep, dim3(40), dim3(256), 0, stream, x, W, ws);
    hipLaunchKernelGGL(k_score, dim3(64, 8), dim3(256), 0, stream, x, W,
                       ws + WS_W2, ws + WS_X2, out + PVAL_OFF, (int*)(out + PIDX_OFF));
    hipLaunchKernelGGL(k_argmin, dim3(4), dim3(256), 0, stream, W, ws + WS_W2,
                       out + PVAL_OFF, (const int*)(out + PIDX_OFF), out, ws);
    hipLaunchKernelGGL(k_bcast, dim3(4096), dim3(256), 0, stream, out, ws);
}

// Round 5
// 635.497 us; speedup vs baseline: 1.0086x; 1.0006x over previous
//
#include <hip/hip_runtime.h>
#include <stdint.h>

typedef float vfloat4 __attribute__((ext_vector_type(4)));

// B=1024, N=8192, D=128
// out layout (floats): quantized[1024][1024][128] | ind[1024] | loss[1]
static const long long QN       = 134217728LL;
static const long long IND_OFF  = QN;
static const long long LOSS_OFF = QN + 1024;

// ws layout (float offsets). ws is 2 GiB; we use ~1.1 MB.
#define WS_W2    0        // 8192 floats
#define WS_X2    8192     // 1024
#define WS_SX    9216     // 128
#define WS_SQ    9344     // 128
#define WS_SQ2   9472     // 1
#define WS_PVAL  16384    // 65536 floats (1024 x 64)
#define WS_PIDX  81920    // 65536 ints
#define WS_Q     147456   // 131072 floats (1024 x 128 gathered codes)

// Fused prep: blocks 0-31 w2 rows; 32-35 x2 rows; 36-39 x column-sums
// (each block owns 32 columns — no atomics) + block 36 zeros sq/Sq2.
__global__ __launch_bounds__(256) void k_prep(const float* __restrict__ x,
                                              const float* __restrict__ W,
                                              float* __restrict__ ws) {
    const int b = blockIdx.x, tid = threadIdx.x;
    if (b < 36) {
        const float4* pr = (b < 32) ? ((const float4*)W + (size_t)(b * 256 + tid) * 32)
                                    : ((const float4*)x + (size_t)((b - 32) * 256 + tid) * 32);
        float s = 0.0f;
#pragma unroll 8
        for (int t = 0; t < 32; ++t) {
            float4 v = pr[t];
            s += v.x * v.x + v.y * v.y + v.z * v.z + v.w * v.w;
        }
        if (b < 32) ws[WS_W2 + b * 256 + tid] = s;
        else        ws[WS_X2 + (b - 32) * 256 + tid] = s;
    } else {
        __shared__ float sh[8][32];
        const int c = tid & 31, g = tid >> 5;
        const int col = (b - 36) * 32 + c;
        float sum = 0.0f;
        for (int r = g; r < 1024; r += 8) sum += x[(size_t)r * 128 + col];
        sh[g][c] = sum;
        __syncthreads();
        if (g == 0) {
            float t = 0.0f;
#pragma unroll
            for (int gg = 0; gg < 8; ++gg) t += sh[gg][c];
            ws[WS_SX + col] = t;
        }
        if (b == 36 && tid < 129) ws[WS_SQ + tid] = 0.0f; // sq[128] + Sq2
    }
}

// dist[m][n] with the reference's fp32 rounding:
//   t = x2[m] - 2*dot(x_m,W_n); s = t + w2[n]
// Per-block partial argmin (first-occurrence tie-break) over a 128-col chunk.
// VERIFIED CORRECT in round 3 — do not perturb the numerics path.
__global__ __launch_bounds__(256) void k_score(
    const float* __restrict__ x, const float* __restrict__ W,
    const float* __restrict__ w2, const float* __restrict__ x2,
    float* __restrict__ pval, int* __restrict__ pidx) {
    __shared__ float Xs[32][132];  // [k][m], +4 pad
    __shared__ float Wst[32][132]; // [k][n]
    const int tid = threadIdx.x;
    const int tx = tid & 15, ty = tid >> 4;
    const int n0 = blockIdx.x * 128, m0 = blockIdx.y * 128;
    const float4* xv = (const float4*)x;
    const float4* wv = (const float4*)W;

    float acc[8][8];
#pragma unroll
    for (int i = 0; i < 8; ++i)
#pragma unroll
        for (int j = 0; j < 8; ++j) acc[i][j] = 0.0f;

    for (int kc = 0; kc < 4; ++kc) {
#pragma unroll
        for (int it = 0; it < 4; ++it) {
            int f = it * 256 + tid;
            int m = f >> 3, kq = f & 7;
            float4 a = xv[(size_t)(m0 + m) * 32 + kc * 8 + kq];
            float4 b = wv[(size_t)(n0 + m) * 32 + kc * 8 + kq];
            Xs[kq * 4 + 0][m] = a.x;
            Xs[kq * 4 + 1][m] = a.y;
            Xs[kq * 4 + 2][m] = a.z;
            Xs[kq * 4 + 3][m] = a.w;
            Wst[kq * 4 + 0][m] = b.x;
            Wst[kq * 4 + 1][m] = b.y;
            Wst[kq * 4 + 2][m] = b.z;
            Wst[kq * 4 + 3][m] = b.w;
        }
        __syncthreads();
#pragma unroll 8
        for (int k = 0; k < 32; ++k) {
            float4 a0 = *(const float4*)&Xs[k][ty * 8];
            float4 a1 = *(const float4*)&Xs[k][ty * 8 + 4];
            float4 b0 = *(const float4*)&Wst[k][tx * 8];
            float4 b1 = *(const float4*)&Wst[k][tx * 8 + 4];
            float af[8] = {a0.x, a0.y, a0.z, a0.w, a1.x, a1.y, a1.z, a1.w};
            float bf[8] = {b0.x, b0.y, b0.z, b0.w, b1.x, b1.y, b1.z, b1.w};
#pragma unroll
            for (int i = 0; i < 8; ++i)
#pragma unroll
                for (int j = 0; j < 8; ++j) acc[i][j] += af[i] * bf[j];
        }
        __syncthreads();
    }

    float w2v[8];
#pragma unroll
    for (int j = 0; j < 8; ++j) w2v[j] = w2[n0 + tx * 8 + j];

#pragma unroll
    for (int i = 0; i < 8; ++i) {
        const int row = m0 + ty * 8 + i;
        const float xxv = x2[row];
        float bestv;
        int besti = n0 + tx * 8;
        {
            float t = xxv - 2.0f * acc[i][0];
            bestv = t + w2v[0];
        }
#pragma unroll
        for (int j = 1; j < 8; ++j) {
            float t = xxv - 2.0f * acc[i][j];
            float s = t + w2v[j];
            if (s < bestv) { bestv = s; besti = n0 + tx * 8 + j; }
        }
        for (int off = 1; off < 16; off <<= 1) {
            float ov = __shfl_xor(bestv, off, 64);
            int oi = __shfl_xor(besti, off, 64);
            if (ov < bestv || (ov == bestv && oi < besti)) { bestv = ov; besti = oi; }
        }
        if (tx == 0) {
            pval[row * 64 + blockIdx.x] = bestv;
            pidx[row * 64 + blockIdx.x] = besti;
        }
    }
}

// Final argmin per row (first-occurrence), write ind, gather q into ws (coalesced),
// Sq2 += w2[ind] (exact identity), sq[d] via coalesced re-gather + 1 atomic/col/block.
__global__ __launch_bounds__(256) void k_argmin(
    const float* __restrict__ W, const float* __restrict__ w2,
    const float* __restrict__ pval, const int* __restrict__ pidx,
    float* __restrict__ out, float* __restrict__ ws) {
    __shared__ int sidx[256];
    __shared__ float sh[2][128];
    const int tid = threadIdx.x;
    const int r = blockIdx.x * 256 + tid; // 0..1023
    float bestv = pval[r * 64];
    int besti = pidx[r * 64];
    for (int c = 1; c < 64; ++c) {
        float v = pval[r * 64 + c];
        if (v < bestv) { bestv = v; besti = pidx[r * 64 + c]; }
    }
    out[IND_OFF + r] = (float)besti;
    sidx[tid] = besti;

    // Sq2 contribution: ||q_r||^2 == w2[ind_r]
    float q2 = w2[besti];
    for (int off = 1; off < 64; off <<= 1) q2 += __shfl_xor(q2, off, 64);
    if ((tid & 63) == 0) atomicAdd(ws + WS_SQ2, q2);
    __syncthreads();

    // Coalesced q gather into ws: 32 iters of (8 rows x 32 float4)
    const int c4 = tid & 31, rg = tid >> 5;
    float4* wsq = (float4*)(ws + WS_Q);
    const float4* wv = (const float4*)W;
#pragma unroll 4
    for (int it = 0; it < 32; ++it) {
        int rr = it * 8 + rg;
        int idx = sidx[rr];
        wsq[(size_t)(blockIdx.x * 256 + rr) * 32 + c4] = wv[(size_t)idx * 32 + c4];
    }

    // Column sums of q over this block's 256 rows (L2-hot rows of W)
    const int d = tid & 127, g = tid >> 7;
    float s = 0.0f;
    for (int rr = g; rr < 256; rr += 2) s += W[(size_t)sidx[rr] * 128 + d];
    sh[g][d] = s;
    __syncthreads();
    if (g == 0) atomicAdd(ws + WS_SQ + d, sh[0][d] + sh[1][d]);
}

// quantized[i][j][:] = q[i]. 537 MB stream write; 8192 blocks x 64 KB.
// Block 0 additionally computes the loss scalar first.
__global__ __launch_bounds__(256) void k_bcast(float* __restrict__ out,
                                               const float* __restrict__ ws) {
    const int bid = blockIdx.x, tid = threadIdx.x;
    if (bid == 0) {
        __shared__ float sh[256];
        float dotv = (tid < 128) ? ws[WS_SX + tid] * ws[WS_SQ + tid] : 0.0f;
        float sx2 = 0.0f;
        for (int r = tid; r < 1024; r += 256) sx2 += ws[WS_X2 + r];
        sh[tid] = dotv;
        __syncthreads();
        for (int s = 128; s > 0; s >>= 1) {
            if (tid < s) sh[tid] += sh[tid + s];
            __syncthreads();
        }
        const float dot = sh[0];
        __syncthreads();
        sh[tid] = sx2;
        __syncthreads();
        for (int s = 128; s > 0; s >>= 1) {
            if (tid < s) sh[tid] += sh[tid + s];
            __syncthreads();
        }
        if (tid == 0) {
            double Sx2 = (double)sh[0], Sq2 = (double)ws[WS_SQ2];
            double loss = 1.25 * (1024.0 * Sx2 + 1024.0 * Sq2 - 2.0 * (double)dot) / 134217728.0;
            out[LOSS_OFF] = (float)loss;
        }
        __syncthreads();
    }
    const int i = bid >> 3;          // row 0..1023
    const int e = bid & 7;           // eighth of the j range
    const int t = tid & 31;
    const vfloat4* src = (const vfloat4*)(ws + WS_Q) + (size_t)i * 32;
    vfloat4 qv = src[t];
    vfloat4* dst = (vfloat4*)out + (size_t)i * 32768 + t;
    const int jend = e * 128 + 128;
    for (int j = e * 128 + (tid >> 5); j < jend; j += 8) {
        dst[(size_t)j * 32] = qv;
    }
}

extern "C" void kernel_launch(void* const* d_in, const int* in_sizes, int n_in,
                              void* d_out, int out_size, void* d_ws, size_t ws_size,
                              hipStream_t stream) {
    const float* x = (const float*)d_in[0]; // 1024 x 128
    const float* W = (const float*)d_in[1]; // 8192 x 128
    float* out = (float*)d_out;
    float* ws = (float*)d_ws;

    hipLaunchKernelGGL(k_prep, dim3(40), dim3(256), 0, stream, x, W, ws);
    hipLaunchKernelGGL(k_score, dim3(64, 8), dim3(256), 0, stream, x, W,
                       ws + WS_W2, ws + WS_X2, ws + WS_PVAL, (int*)(ws + WS_PIDX));
    hipLaunchKernelGGL(k_argmin, dim3(4), dim3(256), 0, stream, W, ws + WS_W2,
                       ws + WS_PVAL, (const int*)(ws + WS_PIDX), out, ws);
    hipLaunchKernelGGL(k_bcast, dim3(8192), dim3(256), 0, stream, out, ws);
}